// Round 16
// baseline (102.405 us; speedup 1.0000x reference)
//
#include <hip/hip_runtime.h>
#include <hip/hip_bf16.h>

#define I_N 16
#define C_N 32
#define L_N 32
#define R_N 36
#define D_N 1024
#define EPSF 1e-8f

typedef _Float16 f16;
typedef __attribute__((ext_vector_type(8))) _Float16 half8;
typedef __attribute__((ext_vector_type(4))) float floatx4;

// async global->LDS, 16B per lane; LDS dest = wave-uniform base + lane*16
__device__ __forceinline__ void gl16(const f16* g, f16* l) {
  __builtin_amdgcn_global_load_lds(
      (const __attribute__((address_space(1))) void*)g,
      (__attribute__((address_space(3))) void*)l, 16, 0, 0);
}

// fast stable tanh via v_exp: tanh(x) = sign(x) * (1-e^{-2|x|})/(1+e^{-2|x|})
__device__ __forceinline__ float fast_tanh(float x) {
  float q = __expf(-2.f * fabsf(x));
  float t = (1.f - q) / (1.f + q);
  return (x >= 0.f) ? t : -t;
}

__device__ __forceinline__ float wave_sum64(float v) {
  #pragma unroll
  for (int off = 32; off > 0; off >>= 1) v += __shfl_xor(v, off, 64);
  return v;
}

// ---------------- K1: wave-per-row Dlw (barrier-free) | imgP = f16(img) padded ----------------
__global__ __launch_bounds__(256) void k_dlw(const float* __restrict__ W,
    const float* __restrict__ simw, const float* __restrict__ tlw,
    const float* __restrict__ img,
    f16* __restrict__ DlwH, f16* __restrict__ imgP) {
  int gw = blockIdx.x * 4 + (threadIdx.x >> 6);
  int lane = threadIdx.x & 63;
  if (gw >= 1024) {                  // ---- imgP branch ----
    int row = gw - 1024;             // 0..767 = i*48 + r
    int i = row / 48, r = row % 48;
    size_t dst = (size_t)row * D_N;
    #pragma unroll
    for (int q = 0; q < 4; ++q) {
      int col = lane * 4 + q * 256;
      f16 h4[4];
      if (r < R_N) {
        size_t src = ((size_t)i * R_N + r) * D_N;
        float4 v = *(const float4*)(img + src + col);
        h4[0] = (f16)v.x; h4[1] = (f16)v.y; h4[2] = (f16)v.z; h4[3] = (f16)v.w;
      } else {
        h4[0] = h4[1] = h4[2] = h4[3] = (f16)0.f;
      }
      *(float2*)(imgP + dst + col) = *(float2*)h4;
    }
    return;
  }
  // ---- Dlw branch (idx==identity -> weights = sigmoid(W)); 16 elems/lane ----
  int row = gw;
  const float* Wr = W + (size_t)row * D_N;
  float w[16]; float p = 0.f;
  #pragma unroll
  for (int q = 0; q < 4; ++q) {
    float4 v = *(const float4*)(Wr + lane * 4 + q * 256);
    w[q*4+0] = 1.f / (1.f + __expf(-v.x));
    w[q*4+1] = 1.f / (1.f + __expf(-v.y));
    w[q*4+2] = 1.f / (1.f + __expf(-v.z));
    w[q*4+3] = 1.f / (1.f + __expf(-v.w));
    p += w[q*4+0] + w[q*4+1] + w[q*4+2] + w[q*4+3];
  }
  float S = wave_sum64(p);
  float mean = S * (1.f / 1024.f);
  p = 0.f;
  #pragma unroll
  for (int k = 0; k < 16; ++k) { float d = w[k] - mean; p += d * d; }
  float S2 = wave_sum64(p);
  float stdv = sqrtf(S2 * (1.f / 1023.f));   // ddof=1
  float thres = mean + simw[row] * stdv;
  float eT = __expf(tlw[0]);
  p = 0.f;
  #pragma unroll
  for (int k = 0; k < 16; ++k) {
    float y = __expf(eT * (w[k] - thres));   // >= 0; inf ok (tanh->1)
    float q2 = __expf(-2.f * y);
    float mp = (1.f - q2) / (1.f + q2);      // tanh(y), y>=0
    w[k] = mp * w[k];
    p += w[k] * w[k];
  }
  float S3 = wave_sum64(p);
  float inv = 1.f / (sqrtf(S3) + EPSF);
  #pragma unroll
  for (int q = 0; q < 4; ++q) {
    f16 h4[4];
    #pragma unroll
    for (int t = 0; t < 4; ++t) h4[t] = (f16)(w[q*4+t] * inv);
    *(float2*)(DlwH + (size_t)row * D_N + lane * 4 + q * 256) = *(float2*)h4;
  }
}

// ---------------- K2: dpart strips (from f16 DlwH) + prefix scan of cap_lens ----------------
__global__ __launch_bounds__(256) void k_dpp(const f16* __restrict__ DlwH,
    const int* __restrict__ lens, float* __restrict__ dpart,
    int* __restrict__ pfx, int* __restrict__ mp) {
  int bid = blockIdx.x;
  if (bid < 64) {
    int p = bid >> 2;                   // 0..15
    int col = (bid & 3) * 256 + threadIdx.x;
    float s = 0.f;
    #pragma unroll 8
    for (int r = p * 64; r < p * 64 + 64; ++r) s += (float)DlwH[(size_t)r * D_N + col];
    dpart[(size_t)p * D_N + col] = s;
  } else if (threadIdx.x < 64) {
    int l = threadIdx.x;
    int v = (l < 32) ? lens[l] : 0;
    int s = v;
    #pragma unroll
    for (int off = 1; off < 32; off <<= 1) {
      int t = __shfl_up(s, off, 64);
      if (l >= off) s += t;
    }
    if (l < 32) pfx[l] = s - v;          // exclusive prefix
    if (l == 31) { pfx[32] = s; mp[0] = s * 16; }
  }
}

// ---------------- K3: qk MFMA + FUSED attn epilogue -> pw ----------------
// A-staging computes f16(cap * diag) on the fly (diag folded from dpart into
// LDS dg[] per block) — k_capd kernel + capD buffer eliminated.
__global__ __launch_bounds__(256) void k_qk(const float* __restrict__ dpart,
    const float* __restrict__ cap, const f16* __restrict__ B,
    const int* __restrict__ lens, const float* __restrict__ tsw,
    float* __restrict__ pw) {
  int mt = blockIdx.x;             // 0..15
  int i  = blockIdx.y;             // 0..15
  int tid = threadIdx.x;
  int w = tid >> 6, lane = tid & 63;
  int l15 = lane & 15, h = lane >> 4;
  __shared__ __align__(16) f16 Als[64 * 32];
  __shared__ __align__(16) f16 Bls[48 * 32];
  __shared__ float att[64][49];    // +1 pad breaks column-sum conflicts
  __shared__ float cn[2][R_N];
  __shared__ __align__(16) float dg[D_N];
  #pragma unroll
  for (int k2 = 0; k2 < 4; ++k2) {     // diag = colsum(dpart)
    int col = tid + k2 * 256;
    float s = 0.f;
    #pragma unroll
    for (int p = 0; p < 16; ++p) s += dpart[(size_t)p * D_N + col];
    dg[col] = s;
  }
  floatx4 acc[3];
  #pragma unroll
  for (int nf = 0; nf < 3; ++nf) acc[nf] = (floatx4)0.f;
  int arow = tid >> 2;             // 0..63
  int u = tid & 3;                 // 16B unit within row
  int vf = (u | ((arow & 1) << 2)) ^ ((arow >> 1) & 7);
  int wofs = (((arow & 62) | (vf >> 2)) * 32) + (vf & 3) * 8;
  const float* Af = cap + (size_t)(mt * 64 + arow) * D_N + u * 8;
  const f16*   Bg = B + (size_t)(i * 48 + arow) * D_N + u * 8;
  int v2 = (h | ((l15 & 1) << 2)) ^ ((l15 >> 1) & 7);
  int rbit = (v2 >> 2) & 1;
  int pun = (v2 & 3) * 8;
  int aoff = (w * 16 + (l15 & 14) + rbit) * 32 + pun;
  int boff[3];
  #pragma unroll
  for (int nf = 0; nf < 3; ++nf) boff[nf] = (nf * 16 + (l15 & 14) + rbit) * 32 + pun;
  __syncthreads();                 // dg ready
  for (int kk = 0; kk < D_N; kk += 32) {
    int cb = kk + u * 8;
    float4 a0 = *(const float4*)(Af + kk);
    float4 a1 = *(const float4*)(Af + kk + 4);
    float4 d0 = *(const float4*)(&dg[cb]);
    float4 d1 = *(const float4*)(&dg[cb + 4]);
    f16 h8[8];
    h8[0] = (f16)(a0.x * d0.x); h8[1] = (f16)(a0.y * d0.y);
    h8[2] = (f16)(a0.z * d0.z); h8[3] = (f16)(a0.w * d0.w);
    h8[4] = (f16)(a1.x * d1.x); h8[5] = (f16)(a1.y * d1.y);
    h8[6] = (f16)(a1.z * d1.z); h8[7] = (f16)(a1.w * d1.w);
    *(float4*)(&Als[wofs]) = *(float4*)h8;
    if (tid < 192) *(float4*)(&Bls[wofs]) = *(const float4*)(Bg + kk);
    __syncthreads();
    half8 a = *(const half8*)(&Als[aoff]);
    #pragma unroll
    for (int nf = 0; nf < 3; ++nf) {
      half8 b = *(const half8*)(&Bls[boff[nf]]);
      acc[nf] = __builtin_amdgcn_mfma_f32_16x16x32_f16(a, b, acc[nf], 0, 0, 0);
    }
    __syncthreads();
  }
  // ---- fused epilogue ----
  int len0 = lens[mt * 2], len1 = lens[mt * 2 + 1];
  #pragma unroll
  for (int nf = 0; nf < 3; ++nf)
    #pragma unroll
    for (int j = 0; j < 4; ++j) {
      int ml = w * 16 + h * 4 + j;           // 0..63
      int n = nf * 16 + l15;                 // 0..47
      float t = fast_tanh(acc[nf][j]);
      float v = (t >= 0.f) ? t : 0.1f * t;   // LeakyReLU(0.1)
      int len = (ml >= 32) ? len1 : len0;
      if ((ml & 31) >= len || n >= R_N) v = 0.f;   // word mask + col pad
      att[ml][n] = v;
    }
  __syncthreads();
  for (int e = tid; e < 2 * R_N; e += 256) {       // word-dim l2norm, per caption
    int cc = e / R_N, r = e % R_N;
    float s = 0.f;
    #pragma unroll
    for (int l = 0; l < 32; ++l) { float a = att[cc * 32 + l][r]; s += a * a; }
    cn[cc][r] = sqrtf(s) + EPSF;
  }
  __syncthreads();
  if (tid < 64) {                                  // softmax over regions, per row
    int cc = tid >> 5, l = tid & 31;
    float smooth = __expf(tsw[0]);
    float mx = -3.4e38f;
    #pragma unroll
    for (int r = 0; r < R_N; ++r) {
      float z = att[tid][r] / cn[cc][r] * smooth;
      att[tid][r] = z;
      mx = fmaxf(mx, z);
    }
    float se = 0.f;
    #pragma unroll
    for (int r = 0; r < R_N; ++r) {
      float e2 = __expf(att[tid][r] - mx);
      att[tid][r] = e2;
      se += e2;
    }
    float inv = 1.f / se;
    float* dst = pw + ((size_t)i * 1024 + (mt * 2 + cc) * 32 + l) * R_N;
    #pragma unroll
    for (int r = 0; r < R_N; ++r) dst[r] = att[tid][r] * inv;
  }
}

// ---------------- K4: ctx = attn @ img[i]; l2norm; * cap -> COMPACT sim_loc (f16) ----------------
__global__ __launch_bounds__(256) void k_ctx(const float* __restrict__ pw,
    const f16* __restrict__ imgP, const float* __restrict__ cap,
    const int* __restrict__ lens, const int* __restrict__ pfx,
    f16* __restrict__ slc) {
  int c  = blockIdx.x;             // 0..31 caption
  int i  = blockIdx.y;             // 0..15 image
  int tid = threadIdx.x;
  int w = tid >> 6;                // wave id
  int cg = tid & 63;
  int len = lens[c];
  int pf = pfx[c];
  __shared__ float pA[32][R_N];
  __shared__ __align__(16) f16 rows[R_N][1024];   // 72 KB
  for (int e = tid; e < 32 * R_N; e += 256) {
    int rr = e / R_N, r = e % R_N;
    pA[rr][r] = pw[((size_t)i * 1024 + c * 32 + rr) * R_N + r];
  }
  const f16* base = imgP + (size_t)i * 48 * D_N;   // padded stride, rows 0..35 used
  #pragma unroll
  for (int t = 0; t < 9; ++t) {
    int rr = w * 9 + t;
    const f16* src = base + (size_t)rr * D_N + cg * 8;
    gl16(src,       &rows[rr][0]);
    gl16(src + 512, &rows[rr][512]);
  }
  __syncthreads();                 // drains vmcnt + lgkm once
  int d0 = cg * 8, d1 = 512 + cg * 8;
  #pragma unroll
  for (int sub = 0; sub < 2; ++sub) {
    float acc[4][16];
    #pragma unroll
    for (int j = 0; j < 4; ++j)
      #pragma unroll
      for (int q = 0; q < 16; ++q) acc[j][q] = 0.f;
    for (int k = 0; k < R_N; ++k) {
      half8 h0 = *(const half8*)(&rows[k][d0]);
      half8 h1 = *(const half8*)(&rows[k][d1]);
      float bv[16];
      #pragma unroll
      for (int q = 0; q < 8; ++q) { bv[q] = (float)h0[q]; bv[8 + q] = (float)h1[q]; }
      #pragma unroll
      for (int j = 0; j < 4; ++j) {
        float a = pA[sub * 16 + w * 4 + j][k];
        #pragma unroll
        for (int q = 0; q < 16; ++q) acc[j][q] += a * bv[q];
      }
    }
    #pragma unroll
    for (int j = 0; j < 4; ++j) {
      int l = sub * 16 + w * 4 + j;      // word index 0..31
      float ss = 0.f;
      #pragma unroll
      for (int q = 0; q < 16; ++q) ss += acc[j][q] * acc[j][q];
      #pragma unroll
      for (int off = 1; off < 64; off <<= 1) ss += __shfl_xor(ss, off, 64);
      if (l < len) {
        float inv = 1.f / (sqrtf(ss) + EPSF);
        const float* capr = cap + ((size_t)c * L_N + l) * D_N;
        float4 c0 = *(const float4*)(capr + d0);
        float4 c1 = *(const float4*)(capr + d0 + 4);
        float4 c2 = *(const float4*)(capr + d1);
        float4 c3 = *(const float4*)(capr + d1 + 4);
        float cv[16] = {c0.x,c0.y,c0.z,c0.w, c1.x,c1.y,c1.z,c1.w,
                        c2.x,c2.y,c2.z,c2.w, c3.x,c3.y,c3.z,c3.w};
        union { f16 h[16]; float4 f4[2]; } u;
        #pragma unroll
        for (int q = 0; q < 16; ++q) u.h[q] = (f16)(acc[j][q] * inv * cv[q]);
        f16* dst = slc + ((size_t)((pf + l) * 16 + i)) * D_N;
        *(float4*)(dst + d0) = u.f4[0];
        *(float4*)(dst + d1) = u.f4[1];
      }
    }
  }
}

// ---------------- K5: big GEMM (compacted M) f16 MFMA, fused rowsum/rowsumsq ----------------
// 128x128 tile, BK=32, 4 waves 2x2. TRIPLE-buffered LDS, depth-2 prefetch via
// global_load_lds + inverse-swizzled global source + swizzled ds_read offsets.
// PERMANENTLY FROZEN R9/R13 structure: depth-1 regressed (R10, vmcnt stall);
// 256x128 regressed (R14, active-blocks < 2/CU kills latency hiding).
__global__ __launch_bounds__(256) void k_gemm(const f16* __restrict__ A,
    const f16* __restrict__ B, const int* __restrict__ mp,
    float* __restrict__ rs16, float* __restrict__ rq16) {
  int bx = blockIdx.x, by = blockIdx.y;
  int Mp = mp[0];
  int m0 = bx * 128, n0 = by * 128;
  if (m0 >= Mp) return;            // uniform per block; compacted tail
  int tid = threadIdx.x;
  int w = tid >> 6, lane = tid & 63;
  int l15 = lane & 15, h = lane >> 4;
  int wm = w >> 1, wn = w & 1;
  __shared__ __align__(16) f16 AB[3][2][128 * 32];   // 48 KB
  floatx4 acc[4][4];
  #pragma unroll
  for (int mf = 0; mf < 4; ++mf)
    #pragma unroll
    for (int nf = 0; nf < 4; ++nf) acc[mf][nf] = (floatx4)0.f;

  // ---- staging: lane's linear LDS slot (r_p,u_p) must receive logical (r_l,u_l)
  int r_p = lane >> 2, u_p = lane & 3;
  int sw = (r_p >> 1) & 7;
  int val = (u_p | ((r_p & 1) << 2)) ^ sw;
  int r_l = (r_p & 14) | (val >> 2);
  int u_l = val & 3;
  const f16* As0 = A + (size_t)(m0 + w * 32 +  0 + r_l) * D_N + u_l * 8;
  const f16* As1 = A + (size_t)(m0 + w * 32 + 16 + r_l) * D_N + u_l * 8;
  const f16* Bs0 = B + (size_t)(n0 + w * 32 +  0 + r_l) * D_N + u_l * 8;
  const f16* Bs1 = B + (size_t)(n0 + w * 32 + 16 + r_l) * D_N + u_l * 8;

  // ---- fragment reads: physical (swizzled) offsets, loop-invariant
  int v2 = (h | ((l15 & 1) << 2)) ^ ((l15 >> 1) & 7);
  int rbit = (v2 >> 2) & 1;
  int pun = (v2 & 3) * 8;
  int aoff[4], boff[4];
  #pragma unroll
  for (int f = 0; f < 4; ++f) {
    aoff[f] = (wm * 64 + f * 16 + (l15 & 14) + rbit) * 32 + pun;
    boff[f] = (wn * 64 + f * 16 + (l15 & 14) + rbit) * 32 + pun;
  }

  #define STAGE(kt, b) { \
    int kof = (kt) * 32; \
    gl16(As0 + kof, &AB[b][0][(w * 32 +  0) * 32]); \
    gl16(As1 + kof, &AB[b][0][(w * 32 + 16) * 32]); \
    gl16(Bs0 + kof, &AB[b][1][(w * 32 +  0) * 32]); \
    gl16(Bs1 + kof, &AB[b][1][(w * 32 + 16) * 32]); }

  #define COMPUTE(b) { \
    half8 af[4], bf[4]; \
    _Pragma("unroll") for (int f = 0; f < 4; ++f) af[f] = *(const half8*)(&AB[b][0][aoff[f]]); \
    _Pragma("unroll") for (int f = 0; f < 4; ++f) bf[f] = *(const half8*)(&AB[b][1][boff[f]]); \
    _Pragma("unroll") for (int mf = 0; mf < 4; ++mf) \
      _Pragma("unroll") for (int nf = 0; nf < 4; ++nf) \
        acc[mf][nf] = __builtin_amdgcn_mfma_f32_16x16x32_f16(af[mf], bf[nf], acc[mf][nf], 0, 0, 0); }

  STAGE(0, 0);
  STAGE(1, 1);
  int cur = 0, n2 = 2;
  for (int kk = 0; kk < 30; ++kk) {
    STAGE(kk + 2, n2);
    asm volatile("s_waitcnt vmcnt(8)" ::: "memory");  // tile kk's 4 loads done
    __builtin_amdgcn_s_barrier();
    __builtin_amdgcn_sched_barrier(0);
    COMPUTE(cur);
    __builtin_amdgcn_s_barrier();                     // all reads of cur done
    cur = (cur == 2) ? 0 : cur + 1;
    n2  = (n2  == 2) ? 0 : n2  + 1;
  }
  asm volatile("s_waitcnt vmcnt(4)" ::: "memory");
  __builtin_amdgcn_s_barrier();
  __builtin_amdgcn_sched_barrier(0);
  COMPUTE(cur);
  __builtin_amdgcn_s_barrier();
  cur = (cur == 2) ? 0 : cur + 1;
  asm volatile("s_waitcnt vmcnt(0)" ::: "memory");
  __builtin_amdgcn_s_barrier();
  __builtin_amdgcn_sched_barrier(0);
  COMPUTE(cur);
  #undef STAGE
  #undef COMPUTE

  int slot = by * 2 + wn;          // 0..15, deterministic partials (no atomics)
  #pragma unroll
  for (int mf = 0; mf < 4; ++mf)
    #pragma unroll
    for (int j = 0; j < 4; ++j) {
      float s = 0.f, q = 0.f;
      #pragma unroll
      for (int nf = 0; nf < 4; ++nf) { float v = acc[mf][nf][j]; s += v; q += v * v; }
      #pragma unroll
      for (int off = 1; off < 16; off <<= 1) { s += __shfl_xor(s, off, 64); q += __shfl_xor(q, off, 64); }
      if (l15 == 0) {
        int m = m0 + wm * 64 + mf * 16 + h * 4 + j;
        rs16[(size_t)slot * 16384 + m] = s;
        rq16[(size_t)slot * 16384 + m] = q;
      }
    }
}

// ---------------- K6: sim[i][c] — one block per (i,c), lane per word (compact rows) ----------------
__global__ __launch_bounds__(64) void k_final(const float* __restrict__ rs16,
    const float* __restrict__ rq16, const int* __restrict__ lens,
    const int* __restrict__ pfx, float* __restrict__ out) {
  int b = blockIdx.x;              // 0..511 = i*32 + c
  int c = b & 31;
  int l = threadIdx.x;             // 0..63, words are 0..31
  int len = lens[c];
  float sv = 0.f;
  if (l < len) {
    int i = b >> 5;
    int row = (pfx[c] + l) * 16 + i;
    float rs = 0.f, rq = 0.f;
    #pragma unroll
    for (int s = 0; s < 16; ++s) {
      rs += rs16[(size_t)s * 16384 + row];
      rq += rq16[(size_t)s * 16384 + row];
    }
    sv = rs / (sqrtf(rq) + EPSF);
  }
  #pragma unroll
  for (int off = 32; off > 0; off >>= 1) sv += __shfl_down(sv, off, 64);
  if (l == 0) out[b] = sv / (float)len;
}

extern "C" void kernel_launch(void* const* d_in, const int* in_sizes, int n_in,
                              void* d_out, int out_size, void* d_ws, size_t ws_size,
                              hipStream_t stream) {
  const float* img  = (const float*)d_in[0];   // (16,36,1024)
  const float* cap  = (const float*)d_in[1];   // (32,32,1024)
  const float* W    = (const float*)d_in[2];   // (1024,1024)
  const float* simw = (const float*)d_in[3];   // (1,1024)
  const float* tsw  = (const float*)d_in[4];   // (1,1)
  const float* tlw  = (const float*)d_in[5];   // (1,1)
  const int*   lens = (const int*)d_in[6];     // (32,)
  float* out = (float*)d_out;

  char* wsB = (char*)d_ws;
  if (ws_size < 51122176) return;   // needs ~48.8 MB scratch
  f16*   DlwH  = (f16*)  (wsB + 4194304);      // 2 MB
  f16*   imgP  = (f16*)  (wsB + 8392704);      // 1.5 MB (768 rows: 48/img, zero-padded)
  float* dpart = (float*)(wsB + 9965568);      // 64 KB
  int*   mp    = (int*)  (wsB + 10031104);
  int*   pfx   = (int*)  (wsB + 10031360);     // 33 ints
  float* pw    = (float*)(wsB + 13111296);     // 2.25 MB (16 x 1024 x 36)
  f16*   slc   = (f16*)  (wsB + 15470592);     // 32 MB (compact rows x 1024)
  float* rs16  = (float*)(wsB + 49025024);     // 1 MB (16 slots x 16384)
  float* rq16  = (float*)(wsB + 50073600);     // 1 MB

  k_dlw<<<448, 256, 0, stream>>>(W, simw, tlw, img, DlwH, imgP);
  k_dpp<<<65, 256, 0, stream>>>(DlwH, lens, dpart, pfx, mp);
  k_qk<<<dim3(16, 16), 256, 0, stream>>>(dpart, cap, imgP, lens, tsw, pw);
  k_ctx<<<dim3(32, 16), 256, 0, stream>>>(pw, imgP, cap, lens, pfx, slc);
  k_gemm<<<dim3(128, 8), 256, 0, stream>>>(slc, DlwH, mp, rs16, rq16);
  k_final<<<512, 64, 0, stream>>>(rs16, rq16, lens, pfx, out);
}

// Round 17
// 94.144 us; speedup vs baseline: 1.0877x; 1.0877x over previous
//
#include <hip/hip_runtime.h>
#include <hip/hip_bf16.h>

#define I_N 16
#define C_N 32
#define L_N 32
#define R_N 36
#define D_N 1024
#define EPSF 1e-8f

typedef _Float16 f16;
typedef __attribute__((ext_vector_type(8))) _Float16 half8;
typedef __attribute__((ext_vector_type(4))) float floatx4;

// async global->LDS, 16B per lane; LDS dest = wave-uniform base + lane*16
__device__ __forceinline__ void gl16(const f16* g, f16* l) {
  __builtin_amdgcn_global_load_lds(
      (const __attribute__((address_space(1))) void*)g,
      (__attribute__((address_space(3))) void*)l, 16, 0, 0);
}

// fast stable tanh via v_exp: tanh(x) = sign(x) * (1-e^{-2|x|})/(1+e^{-2|x|})
__device__ __forceinline__ float fast_tanh(float x) {
  float q = __expf(-2.f * fabsf(x));
  float t = (1.f - q) / (1.f + q);
  return (x >= 0.f) ? t : -t;
}

__device__ __forceinline__ float wave_sum64(float v) {
  #pragma unroll
  for (int off = 32; off > 0; off >>= 1) v += __shfl_xor(v, off, 64);
  return v;
}

// ---------------- K1: wave-per-row Dlw (barrier-free) | imgP = f16(img) padded ----------------
__global__ __launch_bounds__(256) void k_dlw(const float* __restrict__ W,
    const float* __restrict__ simw, const float* __restrict__ tlw,
    const float* __restrict__ img,
    f16* __restrict__ DlwH, f16* __restrict__ imgP) {
  int gw = blockIdx.x * 4 + (threadIdx.x >> 6);
  int lane = threadIdx.x & 63;
  if (gw >= 1024) {                  // ---- imgP branch ----
    int row = gw - 1024;             // 0..767 = i*48 + r
    int i = row / 48, r = row % 48;
    size_t dst = (size_t)row * D_N;
    #pragma unroll
    for (int q = 0; q < 4; ++q) {
      int col = lane * 4 + q * 256;
      f16 h4[4];
      if (r < R_N) {
        size_t src = ((size_t)i * R_N + r) * D_N;
        float4 v = *(const float4*)(img + src + col);
        h4[0] = (f16)v.x; h4[1] = (f16)v.y; h4[2] = (f16)v.z; h4[3] = (f16)v.w;
      } else {
        h4[0] = h4[1] = h4[2] = h4[3] = (f16)0.f;
      }
      *(float2*)(imgP + dst + col) = *(float2*)h4;
    }
    return;
  }
  // ---- Dlw branch (idx==identity -> weights = sigmoid(W)); 16 elems/lane ----
  int row = gw;
  const float* Wr = W + (size_t)row * D_N;
  float w[16]; float p = 0.f;
  #pragma unroll
  for (int q = 0; q < 4; ++q) {
    float4 v = *(const float4*)(Wr + lane * 4 + q * 256);
    w[q*4+0] = 1.f / (1.f + __expf(-v.x));
    w[q*4+1] = 1.f / (1.f + __expf(-v.y));
    w[q*4+2] = 1.f / (1.f + __expf(-v.z));
    w[q*4+3] = 1.f / (1.f + __expf(-v.w));
    p += w[q*4+0] + w[q*4+1] + w[q*4+2] + w[q*4+3];
  }
  float S = wave_sum64(p);
  float mean = S * (1.f / 1024.f);
  p = 0.f;
  #pragma unroll
  for (int k = 0; k < 16; ++k) { float d = w[k] - mean; p += d * d; }
  float S2 = wave_sum64(p);
  float stdv = sqrtf(S2 * (1.f / 1023.f));   // ddof=1
  float thres = mean + simw[row] * stdv;
  float eT = __expf(tlw[0]);
  p = 0.f;
  #pragma unroll
  for (int k = 0; k < 16; ++k) {
    float y = __expf(eT * (w[k] - thres));   // >= 0; inf ok (tanh->1)
    float q2 = __expf(-2.f * y);
    float mp = (1.f - q2) / (1.f + q2);      // tanh(y), y>=0
    w[k] = mp * w[k];
    p += w[k] * w[k];
  }
  float S3 = wave_sum64(p);
  float inv = 1.f / (sqrtf(S3) + EPSF);
  #pragma unroll
  for (int q = 0; q < 4; ++q) {
    f16 h4[4];
    #pragma unroll
    for (int t = 0; t < 4; ++t) h4[t] = (f16)(w[q*4+t] * inv);
    *(float2*)(DlwH + (size_t)row * D_N + lane * 4 + q * 256) = *(float2*)h4;
  }
}

// ---------------- K2: dpart strips (from f16 DlwH) + prefix scan of cap_lens ----------------
__global__ __launch_bounds__(256) void k_dpp(const f16* __restrict__ DlwH,
    const int* __restrict__ lens, float* __restrict__ dpart,
    int* __restrict__ pfx, int* __restrict__ mp) {
  int bid = blockIdx.x;
  if (bid < 64) {
    int p = bid >> 2;                   // 0..15
    int col = (bid & 3) * 256 + threadIdx.x;
    float s = 0.f;
    #pragma unroll 8
    for (int r = p * 64; r < p * 64 + 64; ++r) s += (float)DlwH[(size_t)r * D_N + col];
    dpart[(size_t)p * D_N + col] = s;
  } else if (threadIdx.x < 64) {
    int l = threadIdx.x;
    int v = (l < 32) ? lens[l] : 0;
    int s = v;
    #pragma unroll
    for (int off = 1; off < 32; off <<= 1) {
      int t = __shfl_up(s, off, 64);
      if (l >= off) s += t;
    }
    if (l < 32) pfx[l] = s - v;          // exclusive prefix
    if (l == 31) { pfx[32] = s; mp[0] = s * 16; }
  }
}

// ---------------- K3: capD = f16(cap * diag), diag recomputed from dpart in LDS ----------------
__global__ __launch_bounds__(256) void k_capd(const float* __restrict__ dpart,
    const float* __restrict__ cap, f16* __restrict__ capD) {
  __shared__ float dg[D_N];
  int tid = threadIdx.x;
  #pragma unroll
  for (int k = 0; k < 4; ++k) {
    int col = tid + k * 256;
    float s = 0.f;
    #pragma unroll
    for (int p = 0; p < 16; ++p) s += dpart[(size_t)p * D_N + col];
    dg[col] = s;
  }
  __syncthreads();
  size_t base = (size_t)blockIdx.x * D_N;
  #pragma unroll
  for (int k = 0; k < 4; ++k) {
    int j = tid + k * 256;
    capD[base + j] = (f16)(cap[base + j] * dg[j]);
  }
}

// ---------------- K4: qk MFMA (3-buffer depth-2 pipelined staging) + FUSED attn epilogue ----------------
// A = capD rows mt*64..+63; B = imgP rows i*48..+63 (rows 48..63 staged-but-unread pad).
// Same proven pipeline template as k_gemm: per wave 2 gl16/stage, vmcnt(4)/(2)/(0).
__global__ __launch_bounds__(256) void k_qk(const f16* __restrict__ A,
    const f16* __restrict__ B, const int* __restrict__ lens,
    const float* __restrict__ tsw, float* __restrict__ pw) {
  int mt = blockIdx.x;             // 0..15
  int i  = blockIdx.y;             // 0..15
  int tid = threadIdx.x;
  int w = tid >> 6, lane = tid & 63;
  int l15 = lane & 15, h = lane >> 4;
  __shared__ __align__(16) f16 Abuf[3][64 * 32];   // 12 KB
  __shared__ __align__(16) f16 Bbuf[3][64 * 32];   // 12 KB
  __shared__ float att[64][49];    // +1 pad breaks column-sum conflicts
  __shared__ float cn[2][R_N];
  floatx4 acc[3];
  #pragma unroll
  for (int nf = 0; nf < 3; ++nf) acc[nf] = (floatx4)0.f;

  // staging: lane's linear slot (r_p,u_p) receives logical (r_l,u_l) [gemm involution]
  int r_p = lane >> 2, u_p = lane & 3;
  int sw = (r_p >> 1) & 7;
  int val = (u_p | ((r_p & 1) << 2)) ^ sw;
  int r_l = (r_p & 14) | (val >> 2);
  int u_l = val & 3;
  const f16* Ag = A + (size_t)(mt * 64 + w * 16 + r_l) * D_N + u_l * 8;
  const f16* Bg = B + (size_t)(i * 48 + w * 16 + r_l) * D_N + u_l * 8;

  // fragment reads: physical (swizzled) offsets, loop-invariant
  int v2 = (h | ((l15 & 1) << 2)) ^ ((l15 >> 1) & 7);
  int rbit = (v2 >> 2) & 1;
  int pun = (v2 & 3) * 8;
  int aoff = (w * 16 + (l15 & 14) + rbit) * 32 + pun;
  int boff[3];
  #pragma unroll
  for (int nf = 0; nf < 3; ++nf) boff[nf] = (nf * 16 + (l15 & 14) + rbit) * 32 + pun;

  #define QSTAGE(kt, b) { \
    int kof = (kt) * 32; \
    gl16(Ag + kof, &Abuf[b][(w * 16) * 32]); \
    gl16(Bg + kof, &Bbuf[b][(w * 16) * 32]); }
  #define QCOMPUTE(b) { \
    half8 a = *(const half8*)(&Abuf[b][aoff]); \
    _Pragma("unroll") for (int nf = 0; nf < 3; ++nf) { \
      half8 bb = *(const half8*)(&Bbuf[b][boff[nf]]); \
      acc[nf] = __builtin_amdgcn_mfma_f32_16x16x32_f16(a, bb, acc[nf], 0, 0, 0); } }

  QSTAGE(0, 0);
  QSTAGE(1, 1);
  int cur = 0, n2 = 2;
  for (int kk = 0; kk < 30; ++kk) {
    QSTAGE(kk + 2, n2);
    asm volatile("s_waitcnt vmcnt(4)" ::: "memory");  // stage kk's 2 loads done
    __builtin_amdgcn_s_barrier();
    __builtin_amdgcn_sched_barrier(0);
    QCOMPUTE(cur);
    __builtin_amdgcn_s_barrier();                     // all reads of cur done
    cur = (cur == 2) ? 0 : cur + 1;
    n2  = (n2  == 2) ? 0 : n2  + 1;
  }
  asm volatile("s_waitcnt vmcnt(2)" ::: "memory");
  __builtin_amdgcn_s_barrier();
  __builtin_amdgcn_sched_barrier(0);
  QCOMPUTE(cur);
  __builtin_amdgcn_s_barrier();
  cur = (cur == 2) ? 0 : cur + 1;
  asm volatile("s_waitcnt vmcnt(0)" ::: "memory");
  __builtin_amdgcn_s_barrier();
  __builtin_amdgcn_sched_barrier(0);
  QCOMPUTE(cur);
  #undef QSTAGE
  #undef QCOMPUTE

  // ---- fused epilogue ----
  int len0 = lens[mt * 2], len1 = lens[mt * 2 + 1];
  #pragma unroll
  for (int nf = 0; nf < 3; ++nf)
    #pragma unroll
    for (int j = 0; j < 4; ++j) {
      int ml = w * 16 + h * 4 + j;           // 0..63
      int n = nf * 16 + l15;                 // 0..47
      float t = fast_tanh(acc[nf][j]);
      float v = (t >= 0.f) ? t : 0.1f * t;   // LeakyReLU(0.1)
      int len = (ml >= 32) ? len1 : len0;
      if ((ml & 31) >= len || n >= R_N) v = 0.f;   // word mask + col pad
      att[ml][n] = v;
    }
  __syncthreads();
  for (int e = tid; e < 2 * R_N; e += 256) {       // word-dim l2norm, per caption
    int cc = e / R_N, r = e % R_N;
    float s = 0.f;
    #pragma unroll
    for (int l = 0; l < 32; ++l) { float a = att[cc * 32 + l][r]; s += a * a; }
    cn[cc][r] = sqrtf(s) + EPSF;
  }
  __syncthreads();
  if (tid < 64) {                                  // softmax over regions, per row
    int cc = tid >> 5, l = tid & 31;
    float smooth = __expf(tsw[0]);
    float mx = -3.4e38f;
    #pragma unroll
    for (int r = 0; r < R_N; ++r) {
      float z = att[tid][r] / cn[cc][r] * smooth;
      att[tid][r] = z;
      mx = fmaxf(mx, z);
    }
    float se = 0.f;
    #pragma unroll
    for (int r = 0; r < R_N; ++r) {
      float e2 = __expf(att[tid][r] - mx);
      att[tid][r] = e2;
      se += e2;
    }
    float inv = 1.f / se;
    float* dst = pw + ((size_t)i * 1024 + (mt * 2 + cc) * 32 + l) * R_N;
    #pragma unroll
    for (int r = 0; r < R_N; ++r) dst[r] = att[tid][r] * inv;
  }
}

// ---------------- K5: ctx = attn @ img[i]; l2norm; * cap -> COMPACT sim_loc (f16) ----------------
__global__ __launch_bounds__(256) void k_ctx(const float* __restrict__ pw,
    const f16* __restrict__ imgP, const float* __restrict__ cap,
    const int* __restrict__ lens, const int* __restrict__ pfx,
    f16* __restrict__ slc) {
  int c  = blockIdx.x;             // 0..31 caption
  int i  = blockIdx.y;             // 0..15 image
  int tid = threadIdx.x;
  int w = tid >> 6;                // wave id
  int cg = tid & 63;
  int len = lens[c];
  int pf = pfx[c];
  __shared__ float pA[32][R_N];
  __shared__ __align__(16) f16 rows[R_N][1024];   // 72 KB
  for (int e = tid; e < 32 * R_N; e += 256) {
    int rr = e / R_N, r = e % R_N;
    pA[rr][r] = pw[((size_t)i * 1024 + c * 32 + rr) * R_N + r];
  }
  const f16* base = imgP + (size_t)i * 48 * D_N;   // padded stride, rows 0..35 used
  #pragma unroll
  for (int t = 0; t < 9; ++t) {
    int rr = w * 9 + t;
    const f16* src = base + (size_t)rr * D_N + cg * 8;
    gl16(src,       &rows[rr][0]);
    gl16(src + 512, &rows[rr][512]);
  }
  __syncthreads();                 // drains vmcnt + lgkm once
  int d0 = cg * 8, d1 = 512 + cg * 8;
  #pragma unroll
  for (int sub = 0; sub < 2; ++sub) {
    float acc[4][16];
    #pragma unroll
    for (int j = 0; j < 4; ++j)
      #pragma unroll
      for (int q = 0; q < 16; ++q) acc[j][q] = 0.f;
    for (int k = 0; k < R_N; ++k) {
      half8 h0 = *(const half8*)(&rows[k][d0]);
      half8 h1 = *(const half8*)(&rows[k][d1]);
      float bv[16];
      #pragma unroll
      for (int q = 0; q < 8; ++q) { bv[q] = (float)h0[q]; bv[8 + q] = (float)h1[q]; }
      #pragma unroll
      for (int j = 0; j < 4; ++j) {
        float a = pA[sub * 16 + w * 4 + j][k];
        #pragma unroll
        for (int q = 0; q < 16; ++q) acc[j][q] += a * bv[q];
      }
    }
    #pragma unroll
    for (int j = 0; j < 4; ++j) {
      int l = sub * 16 + w * 4 + j;      // word index 0..31
      float ss = 0.f;
      #pragma unroll
      for (int q = 0; q < 16; ++q) ss += acc[j][q] * acc[j][q];
      #pragma unroll
      for (int off = 1; off < 64; off <<= 1) ss += __shfl_xor(ss, off, 64);
      if (l < len) {
        float inv = 1.f / (sqrtf(ss) + EPSF);
        const float* capr = cap + ((size_t)c * L_N + l) * D_N;
        float4 c0 = *(const float4*)(capr + d0);
        float4 c1 = *(const float4*)(capr + d0 + 4);
        float4 c2 = *(const float4*)(capr + d1);
        float4 c3 = *(const float4*)(capr + d1 + 4);
        float cv[16] = {c0.x,c0.y,c0.z,c0.w, c1.x,c1.y,c1.z,c1.w,
                        c2.x,c2.y,c2.z,c2.w, c3.x,c3.y,c3.z,c3.w};
        union { f16 h[16]; float4 f4[2]; } u;
        #pragma unroll
        for (int q = 0; q < 16; ++q) u.h[q] = (f16)(acc[j][q] * inv * cv[q]);
        f16* dst = slc + ((size_t)((pf + l) * 16 + i)) * D_N;
        *(float4*)(dst + d0) = u.f4[0];
        *(float4*)(dst + d1) = u.f4[1];
      }
    }
  }
}

// ---------------- K6: big GEMM (compacted M) f16 MFMA, fused rowsum/rowsumsq ----------------
// 128x128 tile, BK=32, 4 waves 2x2. TRIPLE-buffered LDS, depth-2 prefetch via
// global_load_lds + inverse-swizzled global source + swizzled ds_read offsets.
// PERMANENTLY FROZEN R9/R13 structure.
__global__ __launch_bounds__(256) void k_gemm(const f16* __restrict__ A,
    const f16* __restrict__ B, const int* __restrict__ mp,
    float* __restrict__ rs16, float* __restrict__ rq16) {
  int bx = blockIdx.x, by = blockIdx.y;
  int Mp = mp[0];
  int m0 = bx * 128, n0 = by * 128;
  if (m0 >= Mp) return;            // uniform per block; compacted tail
  int tid = threadIdx.x;
  int w = tid >> 6, lane = tid & 63;
  int l15 = lane & 15, h = lane >> 4;
  int wm = w >> 1, wn = w & 1;
  __shared__ __align__(16) f16 AB[3][2][128 * 32];   // 48 KB
  floatx4 acc[4][4];
  #pragma unroll
  for (int mf = 0; mf < 4; ++mf)
    #pragma unroll
    for (int nf = 0; nf < 4; ++nf) acc[mf][nf] = (floatx4)0.f;

  int r_p = lane >> 2, u_p = lane & 3;
  int sw = (r_p >> 1) & 7;
  int val = (u_p | ((r_p & 1) << 2)) ^ sw;
  int r_l = (r_p & 14) | (val >> 2);
  int u_l = val & 3;
  const f16* As0 = A + (size_t)(m0 + w * 32 +  0 + r_l) * D_N + u_l * 8;
  const f16* As1 = A + (size_t)(m0 + w * 32 + 16 + r_l) * D_N + u_l * 8;
  const f16* Bs0 = B + (size_t)(n0 + w * 32 +  0 + r_l) * D_N + u_l * 8;
  const f16* Bs1 = B + (size_t)(n0 + w * 32 + 16 + r_l) * D_N + u_l * 8;

  int v2 = (h | ((l15 & 1) << 2)) ^ ((l15 >> 1) & 7);
  int rbit = (v2 >> 2) & 1;
  int pun = (v2 & 3) * 8;
  int aoff[4], boff[4];
  #pragma unroll
  for (int f = 0; f < 4; ++f) {
    aoff[f] = (wm * 64 + f * 16 + (l15 & 14) + rbit) * 32 + pun;
    boff[f] = (wn * 64 + f * 16 + (l15 & 14) + rbit) * 32 + pun;
  }

  #define STAGE(kt, b) { \
    int kof = (kt) * 32; \
    gl16(As0 + kof, &AB[b][0][(w * 32 +  0) * 32]); \
    gl16(As1 + kof, &AB[b][0][(w * 32 + 16) * 32]); \
    gl16(Bs0 + kof, &AB[b][1][(w * 32 +  0) * 32]); \
    gl16(Bs1 + kof, &AB[b][1][(w * 32 + 16) * 32]); }

  #define COMPUTE(b) { \
    half8 af[4], bf[4]; \
    _Pragma("unroll") for (int f = 0; f < 4; ++f) af[f] = *(const half8*)(&AB[b][0][aoff[f]]); \
    _Pragma("unroll") for (int f = 0; f < 4; ++f) bf[f] = *(const half8*)(&AB[b][1][boff[f]]); \
    _Pragma("unroll") for (int mf = 0; mf < 4; ++mf) \
      _Pragma("unroll") for (int nf = 0; nf < 4; ++nf) \
        acc[mf][nf] = __builtin_amdgcn_mfma_f32_16x16x32_f16(af[mf], bf[nf], acc[mf][nf], 0, 0, 0); }

  STAGE(0, 0);
  STAGE(1, 1);
  int cur = 0, n2 = 2;
  for (int kk = 0; kk < 30; ++kk) {
    STAGE(kk + 2, n2);
    asm volatile("s_waitcnt vmcnt(8)" ::: "memory");  // tile kk's 4 loads done
    __builtin_amdgcn_s_barrier();
    __builtin_amdgcn_sched_barrier(0);
    COMPUTE(cur);
    __builtin_amdgcn_s_barrier();                     // all reads of cur done
    cur = (cur == 2) ? 0 : cur + 1;
    n2  = (n2  == 2) ? 0 : n2  + 1;
  }
  asm volatile("s_waitcnt vmcnt(4)" ::: "memory");
  __builtin_amdgcn_s_barrier();
  __builtin_amdgcn_sched_barrier(0);
  COMPUTE(cur);
  __builtin_amdgcn_s_barrier();
  cur = (cur == 2) ? 0 : cur + 1;
  asm volatile("s_waitcnt vmcnt(0)" ::: "memory");
  __builtin_amdgcn_s_barrier();
  __builtin_amdgcn_sched_barrier(0);
  COMPUTE(cur);
  #undef STAGE
  #undef COMPUTE

  int slot = by * 2 + wn;          // 0..15, deterministic partials (no atomics)
  #pragma unroll
  for (int mf = 0; mf < 4; ++mf)
    #pragma unroll
    for (int j = 0; j < 4; ++j) {
      float s = 0.f, q = 0.f;
      #pragma unroll
      for (int nf = 0; nf < 4; ++nf) { float v = acc[mf][nf][j]; s += v; q += v * v; }
      #pragma unroll
      for (int off = 1; off < 16; off <<= 1) { s += __shfl_xor(s, off, 64); q += __shfl_xor(q, off, 64); }
      if (l15 == 0) {
        int m = m0 + wm * 64 + mf * 16 + h * 4 + j;
        rs16[(size_t)slot * 16384 + m] = s;
        rq16[(size_t)slot * 16384 + m] = q;
      }
    }
}

// ---------------- K7: sim[i][c] — one block per (i,c), lane per word (compact rows) ----------------
__global__ __launch_bounds__(64) void k_final(const float* __restrict__ rs16,
    const float* __restrict__ rq16, const int* __restrict__ lens,
    const int* __restrict__ pfx, float* __restrict__ out) {
  int b = blockIdx.x;              // 0..511 = i*32 + c
  int c = b & 31;
  int l = threadIdx.x;             // 0..63, words are 0..31
  int len = lens[c];
  float sv = 0.f;
  if (l < len) {
    int i = b >> 5;
    int row = (pfx[c] + l) * 16 + i;
    float rs = 0.f, rq = 0.f;
    #pragma unroll
    for (int s = 0; s < 16; ++s) {
      rs += rs16[(size_t)s * 16384 + row];
      rq += rq16[(size_t)s * 16384 + row];
    }
    sv = rs / (sqrtf(rq) + EPSF);
  }
  #pragma unroll
  for (int off = 32; off > 0; off >>= 1) sv += __shfl_down(sv, off, 64);
  if (l == 0) out[b] = sv / (float)len;
}

extern "C" void kernel_launch(void* const* d_in, const int* in_sizes, int n_in,
                              void* d_out, int out_size, void* d_ws, size_t ws_size,
                              hipStream_t stream) {
  const float* img  = (const float*)d_in[0];   // (16,36,1024)
  const float* cap  = (const float*)d_in[1];   // (32,32,1024)
  const float* W    = (const float*)d_in[2];   // (1024,1024)
  const float* simw = (const float*)d_in[3];   // (1,1024)
  const float* tsw  = (const float*)d_in[4];   // (1,1)
  const float* tlw  = (const float*)d_in[5];   // (1,1)
  const int*   lens = (const int*)d_in[6];     // (32,)
  float* out = (float*)d_out;

  char* wsB = (char*)d_ws;
  if (ws_size < 51122176) return;   // needs ~48.8 MB scratch
  f16*   DlwH  = (f16*)  (wsB + 4194304);      // 2 MB
  f16*   capD  = (f16*)  (wsB + 6295552);      // 2 MB (cap * diag, f16)
  f16*   imgP  = (f16*)  (wsB + 8392704);      // 1.5 MB (768 rows: 48/img, zero-padded)
  float* dpart = (float*)(wsB + 9965568);      // 64 KB
  int*   mp    = (int*)  (wsB + 10031104);
  int*   pfx   = (int*)  (wsB + 10031360);     // 33 ints
  float* pw    = (float*)(wsB + 13111296);     // 2.25 MB (16 x 1024 x 36)
  f16*   slc   = (f16*)  (wsB + 15470592);     // 32 MB (compact rows x 1024)
  float* rs16  = (float*)(wsB + 49025024);     // 1 MB (16 slots x 16384)
  float* rq16  = (float*)(wsB + 50073600);     // 1 MB

  k_dlw<<<448, 256, 0, stream>>>(W, simw, tlw, img, DlwH, imgP);
  k_dpp<<<65, 256, 0, stream>>>(DlwH, lens, dpart, pfx, mp);
  k_capd<<<1024, 256, 0, stream>>>(dpart, cap, capD);
  k_qk<<<dim3(16, 16), 256, 0, stream>>>(capD, imgP, lens, tsw, pw);
  k_ctx<<<dim3(32, 16), 256, 0, stream>>>(pw, imgP, cap, lens, pfx, slc);
  k_gemm<<<dim3(128, 8), 256, 0, stream>>>(slc, DlwH, mp, rs16, rq16);
  k_final<<<512, 64, 0, stream>>>(rs16, rq16, lens, pfx, out);
}

// Round 18
// 89.254 us; speedup vs baseline: 1.1473x; 1.0548x over previous
//
#include <hip/hip_runtime.h>
#include <hip/hip_bf16.h>

#define I_N 16
#define C_N 32
#define L_N 32
#define R_N 36
#define D_N 1024
#define EPSF 1e-8f

typedef _Float16 f16;
typedef __attribute__((ext_vector_type(8))) _Float16 half8;
typedef __attribute__((ext_vector_type(4))) float floatx4;

// async global->LDS, 16B per lane; LDS dest = wave-uniform base + lane*16
__device__ __forceinline__ void gl16(const f16* g, f16* l) {
  __builtin_amdgcn_global_load_lds(
      (const __attribute__((address_space(1))) void*)g,
      (__attribute__((address_space(3))) void*)l, 16, 0, 0);
}

// fast stable tanh via v_exp: tanh(x) = sign(x) * (1-e^{-2|x|})/(1+e^{-2|x|})
__device__ __forceinline__ float fast_tanh(float x) {
  float q = __expf(-2.f * fabsf(x));
  float t = (1.f - q) / (1.f + q);
  return (x >= 0.f) ? t : -t;
}

__device__ __forceinline__ float wave_sum64(float v) {
  #pragma unroll
  for (int off = 32; off > 0; off >>= 1) v += __shfl_xor(v, off, 64);
  return v;
}

// ---------------- K1: wave-per-row Dlw (barrier-free) | imgP = f16(img) padded ----------------
__global__ __launch_bounds__(256) void k_dlw(const float* __restrict__ W,
    const float* __restrict__ simw, const float* __restrict__ tlw,
    const float* __restrict__ img,
    f16* __restrict__ DlwH, f16* __restrict__ imgP) {
  int gw = blockIdx.x * 4 + (threadIdx.x >> 6);
  int lane = threadIdx.x & 63;
  if (gw >= 1024) {                  // ---- imgP branch ----
    int row = gw - 1024;             // 0..767 = i*48 + r
    int i = row / 48, r = row % 48;
    size_t dst = (size_t)row * D_N;
    #pragma unroll
    for (int q = 0; q < 4; ++q) {
      int col = lane * 4 + q * 256;
      f16 h4[4];
      if (r < R_N) {
        size_t src = ((size_t)i * R_N + r) * D_N;
        float4 v = *(const float4*)(img + src + col);
        h4[0] = (f16)v.x; h4[1] = (f16)v.y; h4[2] = (f16)v.z; h4[3] = (f16)v.w;
      } else {
        h4[0] = h4[1] = h4[2] = h4[3] = (f16)0.f;
      }
      *(float2*)(imgP + dst + col) = *(float2*)h4;
    }
    return;
  }
  // ---- Dlw branch (idx==identity -> weights = sigmoid(W)); 16 elems/lane ----
  int row = gw;
  const float* Wr = W + (size_t)row * D_N;
  float w[16]; float p = 0.f;
  #pragma unroll
  for (int q = 0; q < 4; ++q) {
    float4 v = *(const float4*)(Wr + lane * 4 + q * 256);
    w[q*4+0] = 1.f / (1.f + __expf(-v.x));
    w[q*4+1] = 1.f / (1.f + __expf(-v.y));
    w[q*4+2] = 1.f / (1.f + __expf(-v.z));
    w[q*4+3] = 1.f / (1.f + __expf(-v.w));
    p += w[q*4+0] + w[q*4+1] + w[q*4+2] + w[q*4+3];
  }
  float S = wave_sum64(p);
  float mean = S * (1.f / 1024.f);
  p = 0.f;
  #pragma unroll
  for (int k = 0; k < 16; ++k) { float d = w[k] - mean; p += d * d; }
  float S2 = wave_sum64(p);
  float stdv = sqrtf(S2 * (1.f / 1023.f));   // ddof=1
  float thres = mean + simw[row] * stdv;
  float eT = __expf(tlw[0]);
  p = 0.f;
  #pragma unroll
  for (int k = 0; k < 16; ++k) {
    float y = __expf(eT * (w[k] - thres));   // >= 0; inf ok (tanh->1)
    float q2 = __expf(-2.f * y);
    float mp = (1.f - q2) / (1.f + q2);      // tanh(y), y>=0
    w[k] = mp * w[k];
    p += w[k] * w[k];
  }
  float S3 = wave_sum64(p);
  float inv = 1.f / (sqrtf(S3) + EPSF);
  #pragma unroll
  for (int q = 0; q < 4; ++q) {
    f16 h4[4];
    #pragma unroll
    for (int t = 0; t < 4; ++t) h4[t] = (f16)(w[q*4+t] * inv);
    *(float2*)(DlwH + (size_t)row * D_N + lane * 4 + q * 256) = *(float2*)h4;
  }
}

// ---------------- K2: dpart strips (from f16 DlwH) + prefix scan of cap_lens ----------------
__global__ __launch_bounds__(256) void k_dpp(const f16* __restrict__ DlwH,
    const int* __restrict__ lens, float* __restrict__ dpart,
    int* __restrict__ pfx, int* __restrict__ mp) {
  int bid = blockIdx.x;
  if (bid < 64) {
    int p = bid >> 2;                   // 0..15
    int col = (bid & 3) * 256 + threadIdx.x;
    float s = 0.f;
    #pragma unroll 8
    for (int r = p * 64; r < p * 64 + 64; ++r) s += (float)DlwH[(size_t)r * D_N + col];
    dpart[(size_t)p * D_N + col] = s;
  } else if (threadIdx.x < 64) {
    int l = threadIdx.x;
    int v = (l < 32) ? lens[l] : 0;
    int s = v;
    #pragma unroll
    for (int off = 1; off < 32; off <<= 1) {
      int t = __shfl_up(s, off, 64);
      if (l >= off) s += t;
    }
    if (l < 32) pfx[l] = s - v;          // exclusive prefix
    if (l == 31) { pfx[32] = s; mp[0] = s * 16; }
  }
}

// ---------------- K3: capD = f16(cap * diag); 256 blocks x 4 rows (dg fold amortized) ----------------
__global__ __launch_bounds__(256) void k_capd(const float* __restrict__ dpart,
    const float* __restrict__ cap, f16* __restrict__ capD) {
  __shared__ float dg[D_N];
  int tid = threadIdx.x;
  #pragma unroll
  for (int k = 0; k < 4; ++k) {
    int col = tid + k * 256;
    float s = 0.f;
    #pragma unroll
    for (int p = 0; p < 16; ++p) s += dpart[(size_t)p * D_N + col];
    dg[col] = s;
  }
  __syncthreads();
  #pragma unroll
  for (int rr = 0; rr < 4; ++rr) {
    size_t base = (size_t)(blockIdx.x * 4 + rr) * D_N;
    #pragma unroll
    for (int k = 0; k < 4; ++k) {
      int j = tid + k * 256;
      capD[base + j] = (f16)(cap[base + j] * dg[j]);
    }
  }
}

// ---------------- K4: qk MFMA (3-buffer depth-2 pipelined staging) + FUSED attn epilogue ----------------
// A = capD rows mt*64..+63; B = imgP rows i*48..+63 (rows 48..63 staged-but-unread pad).
// Same proven pipeline template as k_gemm: per wave 2 gl16/stage, vmcnt(4)/(2)/(0).
__global__ __launch_bounds__(256) void k_qk(const f16* __restrict__ A,
    const f16* __restrict__ B, const int* __restrict__ lens,
    const float* __restrict__ tsw, float* __restrict__ pw) {
  int mt = blockIdx.x;             // 0..15
  int i  = blockIdx.y;             // 0..15
  int tid = threadIdx.x;
  int w = tid >> 6, lane = tid & 63;
  int l15 = lane & 15, h = lane >> 4;
  __shared__ __align__(16) f16 Abuf[3][64 * 32];   // 12 KB
  __shared__ __align__(16) f16 Bbuf[3][64 * 32];   // 12 KB
  __shared__ float att[64][49];    // +1 pad breaks column-sum conflicts
  __shared__ float cn[2][R_N];
  floatx4 acc[3];
  #pragma unroll
  for (int nf = 0; nf < 3; ++nf) acc[nf] = (floatx4)0.f;

  // staging: lane's linear slot (r_p,u_p) receives logical (r_l,u_l) [gemm involution]
  int r_p = lane >> 2, u_p = lane & 3;
  int sw = (r_p >> 1) & 7;
  int val = (u_p | ((r_p & 1) << 2)) ^ sw;
  int r_l = (r_p & 14) | (val >> 2);
  int u_l = val & 3;
  const f16* Ag = A + (size_t)(mt * 64 + w * 16 + r_l) * D_N + u_l * 8;
  const f16* Bg = B + (size_t)(i * 48 + w * 16 + r_l) * D_N + u_l * 8;

  // fragment reads: physical (swizzled) offsets, loop-invariant
  int v2 = (h | ((l15 & 1) << 2)) ^ ((l15 >> 1) & 7);
  int rbit = (v2 >> 2) & 1;
  int pun = (v2 & 3) * 8;
  int aoff = (w * 16 + (l15 & 14) + rbit) * 32 + pun;
  int boff[3];
  #pragma unroll
  for (int nf = 0; nf < 3; ++nf) boff[nf] = (nf * 16 + (l15 & 14) + rbit) * 32 + pun;

  #define QSTAGE(kt, b) { \
    int kof = (kt) * 32; \
    gl16(Ag + kof, &Abuf[b][(w * 16) * 32]); \
    gl16(Bg + kof, &Bbuf[b][(w * 16) * 32]); }
  #define QCOMPUTE(b) { \
    half8 a = *(const half8*)(&Abuf[b][aoff]); \
    _Pragma("unroll") for (int nf = 0; nf < 3; ++nf) { \
      half8 bb = *(const half8*)(&Bbuf[b][boff[nf]]); \
      acc[nf] = __builtin_amdgcn_mfma_f32_16x16x32_f16(a, bb, acc[nf], 0, 0, 0); } }

  QSTAGE(0, 0);
  QSTAGE(1, 1);
  int cur = 0, n2 = 2;
  for (int kk = 0; kk < 30; ++kk) {
    QSTAGE(kk + 2, n2);
    asm volatile("s_waitcnt vmcnt(4)" ::: "memory");  // stage kk's 2 loads done
    __builtin_amdgcn_s_barrier();
    __builtin_amdgcn_sched_barrier(0);
    QCOMPUTE(cur);
    __builtin_amdgcn_s_barrier();                     // all reads of cur done
    cur = (cur == 2) ? 0 : cur + 1;
    n2  = (n2  == 2) ? 0 : n2  + 1;
  }
  asm volatile("s_waitcnt vmcnt(2)" ::: "memory");
  __builtin_amdgcn_s_barrier();
  __builtin_amdgcn_sched_barrier(0);
  QCOMPUTE(cur);
  __builtin_amdgcn_s_barrier();
  cur = (cur == 2) ? 0 : cur + 1;
  asm volatile("s_waitcnt vmcnt(0)" ::: "memory");
  __builtin_amdgcn_s_barrier();
  __builtin_amdgcn_sched_barrier(0);
  QCOMPUTE(cur);
  #undef QSTAGE
  #undef QCOMPUTE

  // ---- fused epilogue ----
  int len0 = lens[mt * 2], len1 = lens[mt * 2 + 1];
  #pragma unroll
  for (int nf = 0; nf < 3; ++nf)
    #pragma unroll
    for (int j = 0; j < 4; ++j) {
      int ml = w * 16 + h * 4 + j;           // 0..63
      int n = nf * 16 + l15;                 // 0..47
      float t = fast_tanh(acc[nf][j]);
      float v = (t >= 0.f) ? t : 0.1f * t;   // LeakyReLU(0.1)
      int len = (ml >= 32) ? len1 : len0;
      if ((ml & 31) >= len || n >= R_N) v = 0.f;   // word mask + col pad
      att[ml][n] = v;
    }
  __syncthreads();
  for (int e = tid; e < 2 * R_N; e += 256) {       // word-dim l2norm, per caption
    int cc = e / R_N, r = e % R_N;
    float s = 0.f;
    #pragma unroll
    for (int l = 0; l < 32; ++l) { float a = att[cc * 32 + l][r]; s += a * a; }
    cn[cc][r] = sqrtf(s) + EPSF;
  }
  __syncthreads();
  if (tid < 64) {                                  // softmax over regions, per row
    int cc = tid >> 5, l = tid & 31;
    float smooth = __expf(tsw[0]);
    float mx = -3.4e38f;
    #pragma unroll
    for (int r = 0; r < R_N; ++r) {
      float z = att[tid][r] / cn[cc][r] * smooth;
      att[tid][r] = z;
      mx = fmaxf(mx, z);
    }
    float se = 0.f;
    #pragma unroll
    for (int r = 0; r < R_N; ++r) {
      float e2 = __expf(att[tid][r] - mx);
      att[tid][r] = e2;
      se += e2;
    }
    float inv = 1.f / se;
    float* dst = pw + ((size_t)i * 1024 + (mt * 2 + cc) * 32 + l) * R_N;
    #pragma unroll
    for (int r = 0; r < R_N; ++r) dst[r] = att[tid][r] * inv;
  }
}

// ---------------- K5: ctx = attn @ img[i]; l2norm; * cap -> COMPACT sim_loc (f16) ----------------
// Packed-f16 inner loop: acc in half8 vectors -> v_pk_fma_f16 (2.4x less VALU).
__global__ __launch_bounds__(256) void k_ctx(const float* __restrict__ pw,
    const f16* __restrict__ imgP, const float* __restrict__ cap,
    const int* __restrict__ lens, const int* __restrict__ pfx,
    f16* __restrict__ slc) {
  int c  = blockIdx.x;             // 0..31 caption
  int i  = blockIdx.y;             // 0..15 image
  int tid = threadIdx.x;
  int w = tid >> 6;                // wave id
  int cg = tid & 63;
  int len = lens[c];
  int pf = pfx[c];
  __shared__ float pA[32][R_N];
  __shared__ __align__(16) f16 rows[R_N][1024];   // 72 KB
  for (int e = tid; e < 32 * R_N; e += 256) {
    int rr = e / R_N, r = e % R_N;
    pA[rr][r] = pw[((size_t)i * 1024 + c * 32 + rr) * R_N + r];
  }
  const f16* base = imgP + (size_t)i * 48 * D_N;   // padded stride, rows 0..35 used
  #pragma unroll
  for (int t = 0; t < 9; ++t) {
    int rr = w * 9 + t;
    const f16* src = base + (size_t)rr * D_N + cg * 8;
    gl16(src,       &rows[rr][0]);
    gl16(src + 512, &rows[rr][512]);
  }
  __syncthreads();                 // drains vmcnt + lgkm once
  int d0 = cg * 8, d1 = 512 + cg * 8;
  #pragma unroll
  for (int sub = 0; sub < 2; ++sub) {
    half8 acc0[4], acc1[4];        // f16 accumulators, 16 cols per row
    #pragma unroll
    for (int j = 0; j < 4; ++j) { acc0[j] = (half8)(f16)0.f; acc1[j] = (half8)(f16)0.f; }
    for (int k = 0; k < R_N; ++k) {
      half8 h0 = *(const half8*)(&rows[k][d0]);
      half8 h1 = *(const half8*)(&rows[k][d1]);
      #pragma unroll
      for (int j = 0; j < 4; ++j) {
        f16 ah = (f16)pA[sub * 16 + w * 4 + j][k];
        acc0[j] = acc0[j] + h0 * ah;      // v_pk_fma_f16
        acc1[j] = acc1[j] + h1 * ah;
      }
    }
    #pragma unroll
    for (int j = 0; j < 4; ++j) {
      int l = sub * 16 + w * 4 + j;      // word index 0..31
      float af[16];
      #pragma unroll
      for (int q = 0; q < 8; ++q) { af[q] = (float)acc0[j][q]; af[8 + q] = (float)acc1[j][q]; }
      float ss = 0.f;
      #pragma unroll
      for (int q = 0; q < 16; ++q) ss += af[q] * af[q];
      #pragma unroll
      for (int off = 1; off < 64; off <<= 1) ss += __shfl_xor(ss, off, 64);
      if (l < len) {
        float inv = 1.f / (sqrtf(ss) + EPSF);
        const float* capr = cap + ((size_t)c * L_N + l) * D_N;
        float4 c0 = *(const float4*)(capr + d0);
        float4 c1 = *(const float4*)(capr + d0 + 4);
        float4 c2 = *(const float4*)(capr + d1);
        float4 c3 = *(const float4*)(capr + d1 + 4);
        float cv[16] = {c0.x,c0.y,c0.z,c0.w, c1.x,c1.y,c1.z,c1.w,
                        c2.x,c2.y,c2.z,c2.w, c3.x,c3.y,c3.z,c3.w};
        union { f16 h[16]; float4 f4[2]; } u;
        #pragma unroll
        for (int q = 0; q < 16; ++q) u.h[q] = (f16)(af[q] * inv * cv[q]);
        f16* dst = slc + ((size_t)((pf + l) * 16 + i)) * D_N;
        *(float4*)(dst + d0) = u.f4[0];
        *(float4*)(dst + d1) = u.f4[1];
      }
    }
  }
}

// ---------------- K6: big GEMM (compacted M) f16 MFMA, fused rowsum/rowsumsq ----------------
// 128x128 tile, BK=32, 4 waves 2x2. TRIPLE-buffered LDS, depth-2 prefetch via
// global_load_lds + inverse-swizzled global source + swizzled ds_read offsets.
// PERMANENTLY FROZEN R9/R13 structure.
__global__ __launch_bounds__(256) void k_gemm(const f16* __restrict__ A,
    const f16* __restrict__ B, const int* __restrict__ mp,
    float* __restrict__ rs16, float* __restrict__ rq16) {
  int bx = blockIdx.x, by = blockIdx.y;
  int Mp = mp[0];
  int m0 = bx * 128, n0 = by * 128;
  if (m0 >= Mp) return;            // uniform per block; compacted tail
  int tid = threadIdx.x;
  int w = tid >> 6, lane = tid & 63;
  int l15 = lane & 15, h = lane >> 4;
  int wm = w >> 1, wn = w & 1;
  __shared__ __align__(16) f16 AB[3][2][128 * 32];   // 48 KB
  floatx4 acc[4][4];
  #pragma unroll
  for (int mf = 0; mf < 4; ++mf)
    #pragma unroll
    for (int nf = 0; nf < 4; ++nf) acc[mf][nf] = (floatx4)0.f;

  int r_p = lane >> 2, u_p = lane & 3;
  int sw = (r_p >> 1) & 7;
  int val = (u_p | ((r_p & 1) << 2)) ^ sw;
  int r_l = (r_p & 14) | (val >> 2);
  int u_l = val & 3;
  const f16* As0 = A + (size_t)(m0 + w * 32 +  0 + r_l) * D_N + u_l * 8;
  const f16* As1 = A + (size_t)(m0 + w * 32 + 16 + r_l) * D_N + u_l * 8;
  const f16* Bs0 = B + (size_t)(n0 + w * 32 +  0 + r_l) * D_N + u_l * 8;
  const f16* Bs1 = B + (size_t)(n0 + w * 32 + 16 + r_l) * D_N + u_l * 8;

  int v2 = (h | ((l15 & 1) << 2)) ^ ((l15 >> 1) & 7);
  int rbit = (v2 >> 2) & 1;
  int pun = (v2 & 3) * 8;
  int aoff[4], boff[4];
  #pragma unroll
  for (int f = 0; f < 4; ++f) {
    aoff[f] = (wm * 64 + f * 16 + (l15 & 14) + rbit) * 32 + pun;
    boff[f] = (wn * 64 + f * 16 + (l15 & 14) + rbit) * 32 + pun;
  }

  #define STAGE(kt, b) { \
    int kof = (kt) * 32; \
    gl16(As0 + kof, &AB[b][0][(w * 32 +  0) * 32]); \
    gl16(As1 + kof, &AB[b][0][(w * 32 + 16) * 32]); \
    gl16(Bs0 + kof, &AB[b][1][(w * 32 +  0) * 32]); \
    gl16(Bs1 + kof, &AB[b][1][(w * 32 + 16) * 32]); }

  #define COMPUTE(b) { \
    half8 af[4], bf[4]; \
    _Pragma("unroll") for (int f = 0; f < 4; ++f) af[f] = *(const half8*)(&AB[b][0][aoff[f]]); \
    _Pragma("unroll") for (int f = 0; f < 4; ++f) bf[f] = *(const half8*)(&AB[b][1][boff[f]]); \
    _Pragma("unroll") for (int mf = 0; mf < 4; ++mf) \
      _Pragma("unroll") for (int nf = 0; nf < 4; ++nf) \
        acc[mf][nf] = __builtin_amdgcn_mfma_f32_16x16x32_f16(af[mf], bf[nf], acc[mf][nf], 0, 0, 0); }

  STAGE(0, 0);
  STAGE(1, 1);
  int cur = 0, n2 = 2;
  for (int kk = 0; kk < 30; ++kk) {
    STAGE(kk + 2, n2);
    asm volatile("s_waitcnt vmcnt(8)" ::: "memory");  // tile kk's 4 loads done
    __builtin_amdgcn_s_barrier();
    __builtin_amdgcn_sched_barrier(0);
    COMPUTE(cur);
    __builtin_amdgcn_s_barrier();                     // all reads of cur done
    cur = (cur == 2) ? 0 : cur + 1;
    n2  = (n2  == 2) ? 0 : n2  + 1;
  }
  asm volatile("s_waitcnt vmcnt(4)" ::: "memory");
  __builtin_amdgcn_s_barrier();
  __builtin_amdgcn_sched_barrier(0);
  COMPUTE(cur);
  __builtin_amdgcn_s_barrier();
  cur = (cur == 2) ? 0 : cur + 1;
  asm volatile("s_waitcnt vmcnt(0)" ::: "memory");
  __builtin_amdgcn_s_barrier();
  __builtin_amdgcn_sched_barrier(0);
  COMPUTE(cur);
  #undef STAGE
  #undef COMPUTE

  int slot = by * 2 + wn;          // 0..15, deterministic partials (no atomics)
  #pragma unroll
  for (int mf = 0; mf < 4; ++mf)
    #pragma unroll
    for (int j = 0; j < 4; ++j) {
      float s = 0.f, q = 0.f;
      #pragma unroll
      for (int nf = 0; nf < 4; ++nf) { float v = acc[mf][nf][j]; s += v; q += v * v; }
      #pragma unroll
      for (int off = 1; off < 16; off <<= 1) { s += __shfl_xor(s, off, 64); q += __shfl_xor(q, off, 64); }
      if (l15 == 0) {
        int m = m0 + wm * 64 + mf * 16 + h * 4 + j;
        rs16[(size_t)slot * 16384 + m] = s;
        rq16[(size_t)slot * 16384 + m] = q;
      }
    }
}

// ---------------- K7: sim[i][c] — one block per (i,c), lane per word (compact rows) ----------------
__global__ __launch_bounds__(64) void k_final(const float* __restrict__ rs16,
    const float* __restrict__ rq16, const int* __restrict__ lens,
    const int* __restrict__ pfx, float* __restrict__ out) {
  int b = blockIdx.x;              // 0..511 = i*32 + c
  int c = b & 31;
  int l = threadIdx.x;             // 0..63, words are 0..31
  int len = lens[c];
  float sv = 0.f;
  if (l < len) {
    int i = b >> 5;
    int row = (pfx[c] + l) * 16 + i;
    float rs = 0.f, rq = 0.f;
    #pragma unroll
    for (int s = 0; s < 16; ++s) {
      rs += rs16[(size_t)s * 16384 + row];
      rq += rq16[(size_t)s * 16384 + row];
    }
    sv = rs / (sqrtf(rq) + EPSF);
  }
  #pragma unroll
  for (int off = 32; off > 0; off >>= 1) sv += __shfl_down(sv, off, 64);
  if (l == 0) out[b] = sv / (float)len;
}

extern "C" void kernel_launch(void* const* d_in, const int* in_sizes, int n_in,
                              void* d_out, int out_size, void* d_ws, size_t ws_size,
                              hipStream_t stream) {
  const float* img  = (const float*)d_in[0];   // (16,36,1024)
  const float* cap  = (const float*)d_in[1];   // (32,32,1024)
  const float* W    = (const float*)d_in[2];   // (1024,1024)
  const float* simw = (const float*)d_in[3];   // (1,1024)
  const float* tsw  = (const float*)d_in[4];   // (1,1)
  const float* tlw  = (const float*)d_in[5];   // (1,1)
  const int*   lens = (const int*)d_in[6];     // (32,)
  float* out = (float*)d_out;

  char* wsB = (char*)d_ws;
  if (ws_size < 51122176) return;   // needs ~48.8 MB scratch
  f16*   DlwH  = (f16*)  (wsB + 4194304);      // 2 MB
  f16*   capD  = (f16*)  (wsB + 6295552);      // 2 MB (cap * diag, f16)
  f16*   imgP  = (f16*)  (wsB + 8392704);      // 1.5 MB (768 rows: 48/img, zero-padded)
  float* dpart = (float*)(wsB + 9965568);      // 64 KB
  int*   mp    = (int*)  (wsB + 10031104);
  int*   pfx   = (int*)  (wsB + 10031360);     // 33 ints
  float* pw    = (float*)(wsB + 13111296);     // 2.25 MB (16 x 1024 x 36)
  f16*   slc   = (f16*)  (wsB + 15470592);     // 32 MB (compact rows x 1024)
  float* rs16  = (float*)(wsB + 49025024);     // 1 MB (16 slots x 16384)
  float* rq16  = (float*)(wsB + 50073600);     // 1 MB

  k_dlw<<<448, 256, 0, stream>>>(W, simw, tlw, img, DlwH, imgP);
  k_dpp<<<65, 256, 0, stream>>>(DlwH, lens, dpart, pfx, mp);
  k_capd<<<256, 256, 0, stream>>>(dpart, cap, capD);
  k_qk<<<dim3(16, 16), 256, 0, stream>>>(capD, imgP, lens, tsw, pw);
  k_ctx<<<dim3(32, 16), 256, 0, stream>>>(pw, imgP, cap, lens, pfx, slc);
  k_gemm<<<dim3(128, 8), 256, 0, stream>>>(slc, DlwH, mp, rs16, rq16);
  k_final<<<512, 64, 0, stream>>>(rs16, rq16, lens, pfx, out);
}